// Round 3
// baseline (6112.866 us; speedup 1.0000x reference)
//
#include <hip/hip_runtime.h>

typedef _Float16 f16;
typedef f16   f16x8 __attribute__((ext_vector_type(8)));
typedef float f32x4 __attribute__((ext_vector_type(4)));
typedef unsigned short u16;

#define TSEQ 1024   // T
// B=128, N=M=256, 3M=768 fixed.

__device__ __forceinline__ float sigm(float x) {
    return __builtin_amdgcn_rcpf(1.0f + __expf(-x));
}
__device__ __forceinline__ float tanh_(float x) {
    return 1.0f - 2.0f * __builtin_amdgcn_rcpf(__expf(2.0f * x) + 1.0f);
}

// =====================================================================
// gx = A @ W^T + b_ih   (fp32 in, fp16 internal MFMA, fp16 out to ws)
// A : [128][1024][256] fp32   W : [768][256] fp32   bih : [768] fp32
// ws slice per (t,wgb): 12288 f16, LANE-MAJOR: off = w*1536 + gp*512 +
// lane*8 + (tau*4+i); value = gate gp (0=r,1=z,2=n), col j=w*32+tau*16+c,
// batch b0+q*4+i.  One 16B store per (lane,gp): fully coalesced.
// 8 waves/WG; wave w owns gate-cols {g,256+g,512+g : g in [32w,32w+32)}.
// W fragments (fp16) preloaded to VGPRs: 48 x 4 = 192 VGPRs/lane.
// =====================================================================
__global__ __launch_bounds__(512, 2) void gemm_gx(
    const float* __restrict__ A, const float* __restrict__ W,
    const float* __restrict__ bih, f16* __restrict__ gx, int tc0, int TC)
{
    const int tid  = threadIdx.x;
    const int w    = tid >> 6;
    const int lane = tid & 63;
    const int c    = lane & 15;
    const int q    = lane >> 4;

    f16x8 wf[6][8];
    float bb[6];
#pragma unroll
    for (int k6 = 0; k6 < 6; ++k6) {
        const int g = (k6 >> 1) * 256 + w * 32 + (k6 & 1) * 16 + c;
        bb[k6] = bih[g];
#pragma unroll
        for (int kk = 0; kk < 8; ++kk) {
            const float* wp = W + g * 256 + kk * 32 + q * 8;
            f32x4 w0 = *(const f32x4*)wp, w1 = *(const f32x4*)(wp + 4);
            f16x8 v;
            v[0] = (f16)w0[0]; v[1] = (f16)w0[1]; v[2] = (f16)w0[2]; v[3] = (f16)w0[3];
            v[4] = (f16)w1[0]; v[5] = (f16)w1[1]; v[6] = (f16)w1[2]; v[7] = (f16)w1[3];
            wf[k6][kk] = v;
        }
    }

    const int ntiles = TC * 8;
    for (int tile = blockIdx.x; tile < ntiles; tile += gridDim.x) {
        const int tloc = tile >> 3, wgb = tile & 7;
        const int b0 = wgb * 16, t = tc0 + tloc;

        f32x4 acc[6];
#pragma unroll
        for (int k6 = 0; k6 < 6; ++k6) acc[k6] = (f32x4){0.f, 0.f, 0.f, 0.f};

        const float* Ab = A + ((long)(b0 + c) * TSEQ + t) * 256;   // A-frag row m=c
#pragma unroll
        for (int kk = 0; kk < 8; ++kk) {
            f32x4 a0 = *(const f32x4*)(Ab + kk * 32 + q * 8);
            f32x4 a1 = *(const f32x4*)(Ab + kk * 32 + q * 8 + 4);
            f16x8 a;
            a[0] = (f16)a0[0]; a[1] = (f16)a0[1]; a[2] = (f16)a0[2]; a[3] = (f16)a0[3];
            a[4] = (f16)a1[0]; a[5] = (f16)a1[1]; a[6] = (f16)a1[2]; a[7] = (f16)a1[3];
#pragma unroll
            for (int k6 = 0; k6 < 6; ++k6)
                acc[k6] = __builtin_amdgcn_mfma_f32_16x16x32_f16(a, wf[k6][kk], acc[k6], 0, 0, 0);
        }

        f16* gb = gx + (long)tile * 12288;
#pragma unroll
        for (int gp = 0; gp < 3; ++gp) {
            f16x8 v;
#pragma unroll
            for (int e = 0; e < 8; ++e) {
                const int tau = e >> 2, i = e & 3;
                v[e] = (f16)(acc[gp * 2 + tau][i] + bb[gp * 2 + tau]);
            }
            *(f16x8*)(gb + w * 1536 + gp * 512 + lane * 8) = v;
        }
    }
}

// =====================================================================
// GRU recurrence, one chunk of TC steps. Grid = 8 WGs x 512 thr (16 batch
// rows per WG). w_hh fp16 fragments in VGPRs (192); h fp16 in LDS (A-frag
// layout, row stride 264) + fp16 in regs; gx slice prefetched to VGPRs one
// step ahead, staged to LDS double buffer. Two barriers per step.
// n = tanh(gx_n + b_ih_n + r*(gh_n + b_hh_n)); b_ih folded in gemm.
// h carried across chunk launches in ws (fp32 of the fp16 state).
// =====================================================================
__global__ __launch_bounds__(512, 2) void gru_rec(
    const f16* __restrict__ gx, const float* __restrict__ Whh,
    const float* __restrict__ bhh, float* __restrict__ hcarry,
    float* __restrict__ out, float* __restrict__ hid,
    int tc0, int TC, int first, int last)
{
    __shared__ __align__(16) f16 gxb[2][12288];
    __shared__ __align__(16) f16 hbuf[16 * 264];

    const int tid  = threadIdx.x;
    const int w    = tid >> 6;
    const int lane = tid & 63;
    const int c    = lane & 15;
    const int q    = lane >> 4;
    const int wgb  = blockIdx.x;
    const int b0   = wgb * 16;

    // w_hh -> fp16 fragments
    f16x8 wf[6][8];
#pragma unroll
    for (int k6 = 0; k6 < 6; ++k6) {
        const int g = (k6 >> 1) * 256 + w * 32 + (k6 & 1) * 16 + c;
#pragma unroll
        for (int kk = 0; kk < 8; ++kk) {
            const float* wp = Whh + g * 256 + kk * 32 + q * 8;
            f32x4 w0 = *(const f32x4*)wp, w1 = *(const f32x4*)(wp + 4);
            f16x8 v;
            v[0] = (f16)w0[0]; v[1] = (f16)w0[1]; v[2] = (f16)w0[2]; v[3] = (f16)w0[3];
            v[4] = (f16)w1[0]; v[5] = (f16)w1[1]; v[6] = (f16)w1[2]; v[7] = (f16)w1[3];
            wf[k6][kk] = v;
        }
    }

    // biases (f16-packed to save regs; |b|<0.3 so fp16 exact to 2^-12)
    f16 bhv[6];
#pragma unroll
    for (int tau = 0; tau < 2; ++tau) {
        const int j = w * 32 + tau * 16 + c;
        bhv[0 + tau] = (f16)bhh[j];
        bhv[2 + tau] = (f16)bhh[256 + j];
        bhv[4 + tau] = (f16)bhh[512 + j];
    }

    // h state: fp16 in regs (lane owns batch q*4+i, col j=w*32+tau*16+c)
    f16 hreg[8];
#pragma unroll
    for (int e = 0; e < 8; ++e) {
        const int tau = e >> 2, i = e & 3;
        float hv = first ? 0.f : hcarry[(long)(b0 + q * 4 + i) * 256 + w * 32 + tau * 16 + c];
        hreg[e] = (f16)hv;
        hbuf[(q * 4 + i) * 264 + w * 32 + tau * 16 + c] = hreg[e];
    }

    // stage gx[tc0] into gxb[0]
    {
        const f16* sl = gx + (long)wgb * 12288;
#pragma unroll
        for (int gp = 0; gp < 3; ++gp) {
            f16x8 p = *(const f16x8*)(sl + w * 1536 + gp * 512 + lane * 8);
            *(f16x8*)(&gxb[0][w * 1536 + gp * 512 + lane * 8]) = p;
        }
    }
    __syncthreads();

    int cur = 0;
    for (int tl = 0; tl < TC; ++tl) {
        const int t = tc0 + tl;

        // ---- phase 1: read gx + gh = h @ Whh^T (48 MFMA/wave) ----
        f16x8 gv0 = *(const f16x8*)(&gxb[cur][w * 1536 +          lane * 8]);
        f16x8 gv1 = *(const f16x8*)(&gxb[cur][w * 1536 +  512 +   lane * 8]);
        f16x8 gxn = *(const f16x8*)(&gxb[cur][w * 1536 + 1024 +   lane * 8]);

        f32x4 acc[6];
#pragma unroll
        for (int tau = 0; tau < 2; ++tau) {
#pragma unroll
            for (int i = 0; i < 4; ++i) {
                acc[tau][i]     = (float)gv0[tau * 4 + i] + (float)bhv[0 + tau];
                acc[2 + tau][i] = (float)gv1[tau * 4 + i] + (float)bhv[2 + tau];
                acc[4 + tau][i] = (float)bhv[4 + tau];
            }
        }
#pragma unroll
        for (int kk = 0; kk < 8; ++kk) {
            f16x8 a = *(const f16x8*)(hbuf + c * 264 + kk * 32 + q * 8);
#pragma unroll
            for (int k6 = 0; k6 < 6; ++k6)
                acc[k6] = __builtin_amdgcn_mfma_f32_16x16x32_f16(a, wf[k6][kk], acc[k6], 0, 0, 0);
        }

        // ---- prefetch gx[t+1] into regs (latency covered by barrier+phase2)
        const int tln = (tl + 1 < TC) ? tl + 1 : tl;
        const f16* sl = gx + (long)(tln * 8 + wgb) * 12288;
        f16x8 p0 = *(const f16x8*)(sl + w * 1536 +        lane * 8);
        f16x8 p1 = *(const f16x8*)(sl + w * 1536 +  512 + lane * 8);
        f16x8 p2 = *(const f16x8*)(sl + w * 1536 + 1024 + lane * 8);

        __syncthreads();   // all waves' h reads done

        // ---- stage prefetch to other LDS buffer ----
        *(f16x8*)(&gxb[1 - cur][w * 1536 +        lane * 8]) = p0;
        *(f16x8*)(&gxb[1 - cur][w * 1536 +  512 + lane * 8]) = p1;
        *(f16x8*)(&gxb[1 - cur][w * 1536 + 1024 + lane * 8]) = p2;

        // ---- phase 2: gates + h update ----
#pragma unroll
        for (int tau = 0; tau < 2; ++tau) {
            const int j = w * 32 + tau * 16 + c;
#pragma unroll
            for (int i = 0; i < 4; ++i) {
                const int b = q * 4 + i;
                float r = sigm(acc[tau][i]);
                float z = sigm(acc[2 + tau][i]);
                float n = tanh_((float)gxn[tau * 4 + i] + r * acc[4 + tau][i]);
                float hp = (float)hreg[tau * 4 + i];
                float h = n + z * (hp - n);
                f16 hh = (f16)h;
                hreg[tau * 4 + i] = hh;
                hbuf[b * 264 + j] = hh;
                out[((long)(b0 + b) * TSEQ + t) * 256 + j] = h;
            }
        }
        __syncthreads();   // h(t+1) + gx stage visible
        cur ^= 1;
    }

    // persist h across chunks; final h_n if last chunk
#pragma unroll
    for (int e = 0; e < 8; ++e) {
        const int tau = e >> 2, i = e & 3;
        const long idx = (long)(b0 + q * 4 + i) * 256 + w * 32 + tau * 16 + c;
        hcarry[idx] = (float)hreg[e];
        if (last) hid[idx] = (float)hreg[e];
    }
}

// =====================================================================
extern "C" void kernel_launch(void* const* d_in, const int* in_sizes, int n_in,
                              void* d_out, int out_size, void* d_ws, size_t ws_size,
                              hipStream_t stream) {
    const float* X    = (const float*)d_in[0];
    const float* wih0 = (const float*)d_in[1];
    const float* whh0 = (const float*)d_in[2];
    const float* bih0 = (const float*)d_in[3];
    const float* bhh0 = (const float*)d_in[4];
    const float* wih1 = (const float*)d_in[5];
    const float* whh1 = (const float*)d_in[6];
    const float* bih1 = (const float*)d_in[7];
    const float* bhh1 = (const float*)d_in[8];

    float* out = (float*)d_out;                       // [128][1024][256] fp32
    float* hid = out + (long)128 * TSEQ * 256;        // [2][128][256] fp32

    // ws: [hcarry fp32 128x256 = 128KiB][gx f16 chunk: TC*8*12288*2 bytes]
    float* hcarry = (float*)d_ws;
    f16*   gxws   = (f16*)((char*)d_ws + 131072);

    int TC = TSEQ;
    while (TC > 16 && (size_t)131072 + (size_t)TC * 196608 > ws_size) TC >>= 1;

    const float* wih[2] = {wih0, wih1};
    const float* whh[2] = {whh0, whh1};
    const float* bih[2] = {bih0, bih1};
    const float* bhh[2] = {bhh0, bhh1};

    for (int layer = 0; layer < 2; ++layer) {
        const float* Ain = layer ? out : X;   // out0 staged in d_out region
        for (int tc0 = 0; tc0 < TSEQ; tc0 += TC) {
            const int ntiles = TC * 8;
            const int grid = ntiles < 512 ? ntiles : 512;
            gemm_gx<<<grid, 512, 0, stream>>>(Ain, wih[layer], bih[layer], gxws, tc0, TC);
            gru_rec<<<8, 512, 0, stream>>>(gxws, whh[layer], bhh[layer], hcarry,
                                           out, hid + (long)layer * 128 * 256,
                                           tc0, TC, tc0 == 0, tc0 + TC == TSEQ);
        }
    }
}